// Round 4
// baseline (130.156 us; speedup 1.0000x reference)
//
#include <hip/hip_runtime.h>

#define Wd 64
#define Hd 64
#define HWp 4096
#define CIN_ 128
#define COUT_ 128

typedef __bf16 bf16x8 __attribute__((ext_vector_type(8)));
typedef float f32x4 __attribute__((ext_vector_type(4)));

__device__ inline ushort f2bf(float f) {
    unsigned u = __float_as_uint(f);
    u += 0x7fff + ((u >> 16) & 1);          // round-to-nearest-even
    return (ushort)(u >> 16);
}
__device__ inline float bflo(unsigned u) { return __uint_as_float(u << 16); }
__device__ inline float bfhi(unsigned u) { return __uint_as_float(u & 0xffff0000u); }
__device__ inline unsigned bfround(float f) {
    unsigned u = __float_as_uint(f);
    return u + 0x7fff + ((u >> 16) & 1);
}
__device__ inline unsigned pack2(float lo, float hi) {
    return __builtin_amdgcn_perm(bfround(hi), bfround(lo), 0x07060302);
}

// ---------------------------------------------------------------------------
// K_A (one launch, 1344 blocks):
//   blk 0..255    : transpose x NCHW f32 -> xt[b][yx][c] bf16
//   blk 256..831  : repack main w -> bf16 w_t2 in MFMA A-fragment order:
//                   [(((s*2+wm)*4+i)*64 + lane)*8 + j]
//                   (s = tap*4+q, o = wm*64+i*16+(lane&15),
//                    c = (s&3)*32+(lane>>4)*8+j, k = s>>2)
//   blk 832..1343 : offset conv (4 ch) + bilinear metadata per (b,k,p)
// ---------------------------------------------------------------------------
__global__ __launch_bounds__(256) void prep_offsets_kernel(
    const float* __restrict__ x, const float* __restrict__ w,
    const float* __restrict__ w_off, const float* __restrict__ b_off,
    ushort* __restrict__ xt, ushort* __restrict__ w_t2,
    int4* __restrict__ midx, float4* __restrict__ mw)
{
    __shared__ char smem[34816];
    int blk = blockIdx.x;
    int t = threadIdx.x;

    if (blk < 256) {
        // ---- transpose x to NHWC bf16 ----
        ushort* tile = (ushort*)smem;                 // [128][136]
        int b = blk >> 5, yx0 = (blk & 31) << 7;
        const float* xb = x + (size_t)b * CIN_ * HWp + yx0;
        int lanelo = t & 31, grp = t >> 5;
        #pragma unroll
        for (int i = 0; i < 4; i++) {
            int cbase = i * 32 + grp * 4;
            float4 v0 = *(const float4*)(xb + (size_t)(cbase + 0) * HWp + lanelo * 4);
            float4 v1 = *(const float4*)(xb + (size_t)(cbase + 1) * HWp + lanelo * 4);
            float4 v2 = *(const float4*)(xb + (size_t)(cbase + 2) * HWp + lanelo * 4);
            float4 v3 = *(const float4*)(xb + (size_t)(cbase + 3) * HWp + lanelo * 4);
            ushort4 u;
            u.x = f2bf(v0.x); u.y = f2bf(v1.x); u.z = f2bf(v2.x); u.w = f2bf(v3.x);
            *(ushort4*)&tile[(lanelo * 4 + 0) * 136 + cbase] = u;
            u.x = f2bf(v0.y); u.y = f2bf(v1.y); u.z = f2bf(v2.y); u.w = f2bf(v3.y);
            *(ushort4*)&tile[(lanelo * 4 + 1) * 136 + cbase] = u;
            u.x = f2bf(v0.z); u.y = f2bf(v1.z); u.z = f2bf(v2.z); u.w = f2bf(v3.z);
            *(ushort4*)&tile[(lanelo * 4 + 2) * 136 + cbase] = u;
            u.x = f2bf(v0.w); u.y = f2bf(v1.w); u.z = f2bf(v2.w); u.w = f2bf(v3.w);
            *(ushort4*)&tile[(lanelo * 4 + 3) * 136 + cbase] = u;
        }
        __syncthreads();
        ushort* dst = xt + ((size_t)b * HWp + yx0) * CIN_;
        int c8 = (t & 15) * 8, yxg = t >> 4;
        #pragma unroll
        for (int i = 0; i < 8; i++) {
            int yxl = i * 16 + yxg;
            int4 v = *(int4*)&tile[yxl * 136 + c8];
            *(int4*)(dst + (size_t)yxl * CIN_ + c8) = v;
        }
    } else if (blk < 832) {
        // ---- repack main w into MFMA A-fragment order ----
        int i = (blk - 256) * 256 + t;               // 147456 total
        int j    = i & 7;
        int lane = (i >> 3) & 63;
        int ii   = (i >> 9) & 3;
        int wm   = (i >> 11) & 1;
        int s    = i >> 12;
        int o = wm * 64 + ii * 16 + (lane & 15);
        int c = (s & 3) * 32 + (lane >> 4) * 8 + j;
        int k = s >> 2;
        w_t2[i] = f2bf(w[o * 1152 + c * 9 + k]);
    } else {
        // ---- offset conv + bilinear metadata ----
        float* wl   = (float*)smem;                   // 4608 f
        float* part = (float*)(smem + 18432);         // 1024 f
        float* der  = (float*)(smem + 22528);         // 256 f
        int blk2 = blk - 832;
        int b = blk2 >> 6;
        int h = blk2 & 63;

        for (int i = t; i < 4608; i += 256) {
            int j = i / 1152;
            int r = i - j * 1152;                     // c*9 + tap
            wl[r * 4 + j] = w_off[i];
        }
        __syncthreads();

        int pi = t & 63, cc = t >> 6;
        const float* xb = x + (size_t)(b * CIN_ + cc * 32) * HWp;

        int idx9[9];
        float msk9[9];
        #pragma unroll
        for (int dy = 0; dy < 3; dy++) {
            int hy = h + dy - 1;
            int hyc = min(max(hy, 0), Hd - 1);
            bool vr = (hy >= 0) && (hy < Hd);
            #pragma unroll
            for (int dx = 0; dx < 3; dx++) {
                int wx = pi + dx - 1;
                int wxc = min(max(wx, 0), Wd - 1);
                bool v = vr && (wx >= 0) && (wx < Wd);
                idx9[dy * 3 + dx] = hyc * Wd + wxc;
                msk9[dy * 3 + dx] = v ? 1.0f : 0.0f;
            }
        }

        float o0 = 0.f, o1 = 0.f, o2 = 0.f, o3 = 0.f;
        #pragma unroll 2
        for (int c = 0; c < 32; c++) {
            const float* xp = xb + c * HWp;
            const float* wc = &wl[(cc * 32 + c) * 36];
            float xv[9];
            #pragma unroll
            for (int tp = 0; tp < 9; tp++) xv[tp] = xp[idx9[tp]] * msk9[tp];
            #pragma unroll
            for (int tp = 0; tp < 9; tp++) {
                float4 wj = *(const float4*)&wc[tp * 4];
                o0 += xv[tp] * wj.x; o1 += xv[tp] * wj.y;
                o2 += xv[tp] * wj.z; o3 += xv[tp] * wj.w;
            }
        }
        part[t * 4 + 0] = o0;
        part[t * 4 + 1] = o1;
        part[t * 4 + 2] = o2;
        part[t * 4 + 3] = o3;
        __syncthreads();

        if (t < 64) {
            float s0 = b_off[0], s1 = b_off[1], s2 = b_off[2], s3 = b_off[3];
            #pragma unroll
            for (int q = 0; q < 4; q++) {
                s0 += part[(q * 64 + t) * 4 + 0];
                s1 += part[(q * 64 + t) * 4 + 1];
                s2 += part[(q * 64 + t) * 4 + 2];
                s3 += part[(q * 64 + t) * 4 + 3];
            }
            der[t * 4 + 0] = s0;
            der[t * 4 + 1] = s1;
            der[t * 4 + 2] = fmaxf(s2, 0.f) + 1.f;
            der[t * 4 + 3] = fmaxf(s3, 0.f) + 1.f;
        }
        __syncthreads();

        #pragma unroll
        for (int s = 0; s < 3; s++) {
            int q = t + s * 256;
            if (q < 576) {
                int k = q >> 6;
                int pp = q & 63;
                float sy = der[pp * 4 + 0], sx = der[pp * 4 + 1];
                float sc1 = der[pp * 4 + 2], sc2 = der[pp * 4 + 3];
                int ky = k / 3, kx = k - ky * 3;
                float by = (float)(ky - 1), bx = (float)(kx - 1);
                bool corner = (ky != 1) && (kx != 1);
                bool edge = (ky != 1) ^ (kx != 1);
                float sk = corner ? sc1 : (edge ? sc2 : 0.0f);
                float py = (float)h + by * sk + sy;
                float px = (float)pp + bx * sk + sx;
                float y0f = floorf(py), x0f = floorf(px);
                float wy = py - y0f, wx = px - x0f;
                int y0 = (int)y0f, x0 = (int)x0f;
                int y1 = y0 + 1, x1 = x0 + 1;
                float vy0 = (y0 >= 0 && y0 < Hd) ? 1.f : 0.f;
                float vy1 = (y1 >= 0 && y1 < Hd) ? 1.f : 0.f;
                float vx0 = (x0 >= 0 && x0 < Wd) ? 1.f : 0.f;
                float vx1 = (x1 >= 0 && x1 < Wd) ? 1.f : 0.f;
                int cy0 = min(max(y0, 0), Hd - 1), cy1 = min(max(y1, 0), Hd - 1);
                int cx0 = min(max(x0, 0), Wd - 1), cx1 = min(max(x1, 0), Wd - 1);
                int4 ii;
                ii.x = cy0 * Wd + cx0;
                ii.y = cy0 * Wd + cx1;
                ii.z = cy1 * Wd + cx0;
                ii.w = cy1 * Wd + cx1;
                float4 ww;
                ww.x = (1.f - wy) * (1.f - wx) * vy0 * vx0;
                ww.y = (1.f - wy) * wx * vy0 * vx1;
                ww.z = wy * (1.f - wx) * vy1 * vx0;
                ww.w = wy * wx * vy1 * vx1;
                int addr = (b * 9 + k) * HWp + h * Wd + pp;
                midx[addr] = ii;
                mw[addr] = ww;
            }
        }
    }
}

// ---------------------------------------------------------------------------
// K3: fused gather (NHWC-bf16) + bf16 MFMA GEMM.
// Block = (b, h-row): M=128, N=64, K=1152 in 36 chunks of 32 c.
// 256 thr = 4 waves (2 M x 2 N), wave tile 64x32.
// A loaded global->reg in fragment order (L2-resident, no LDS, no barrier
// dep). S only in LDS, double-buffered. 512 blocks = 2 blocks/CU so barrier
// stalls overlap across blocks.
// ---------------------------------------------------------------------------
struct Gath { int4 g0, g1, g2, g3; int4 a0, a1, a2, a3; };

__global__ __launch_bounds__(256, 2) void deform_gemm_mfma(
    const ushort* __restrict__ xt, const ushort* __restrict__ w_t2,
    const float* __restrict__ bias, const int4* __restrict__ midx,
    const float4* __restrict__ mw, float* __restrict__ out)
{
    __shared__ ushort S_lds[2][64 * 40];

    int t = threadIdx.x;
    int b = blockIdx.x >> 6;
    int h = blockIdx.x & 63;
    int p0 = h << 6;
    const ushort* xtb = xt + (size_t)b * HWp * CIN_;

    int p = t >> 2;                 // 0..63 position in row
    int c8 = (t & 3) << 3;          // channel offset in 32-chunk

    int wv = t >> 6, lane = t & 63;
    int wm = wv & 1, wn = wv >> 1;  // 2 x 2 waves
    int lm = lane & 15, lq = lane >> 4;

    f32x4 acc[4][2] = {};

    int4 mi = midx[(b * 9 + 0) * HWp + p0 + p];
    float4 mv = mw[(b * 9 + 0) * HWp + p0 + p];

    auto issue = [&](int s) -> Gath {
        int q = s & 3;
        const ushort* base = xtb + q * 32 + c8;
        Gath r;
        r.g0 = *(const int4*)(base + mi.x * CIN_);
        r.g1 = *(const int4*)(base + mi.y * CIN_);
        r.g2 = *(const int4*)(base + mi.z * CIN_);
        r.g3 = *(const int4*)(base + mi.w * CIN_);
        const ushort* ab = w_t2 + (size_t)(((s * 2 + wm) * 4) * 64 + lane) * 8;
        r.a0 = *(const int4*)(ab);
        r.a1 = *(const int4*)(ab + 512);
        r.a2 = *(const int4*)(ab + 1024);
        r.a3 = *(const int4*)(ab + 1536);
        return r;
    };
    auto commitS = [&](int nb, const Gath& G) {
        const unsigned* u0 = (const unsigned*)&G.g0;
        const unsigned* u1 = (const unsigned*)&G.g1;
        const unsigned* u2 = (const unsigned*)&G.g2;
        const unsigned* u3 = (const unsigned*)&G.g3;
        unsigned sd[4];
        #pragma unroll
        for (int d = 0; d < 4; d++) {
            float vlo = mv.x * bflo(u0[d]) + mv.y * bflo(u1[d])
                      + mv.z * bflo(u2[d]) + mv.w * bflo(u3[d]);
            float vhi = mv.x * bfhi(u0[d]) + mv.y * bfhi(u1[d])
                      + mv.z * bfhi(u2[d]) + mv.w * bfhi(u3[d]);
            sd[d] = pack2(vlo, vhi);
        }
        *(int4*)&S_lds[nb][p * 40 + c8] = *(const int4*)sd;
    };

    Gath Gc = issue(0);
    commitS(0, Gc);
    __syncthreads();

    for (int s = 0; s < 36; s++) {
        int cur = s & 1;
        bool prod = (s + 1 < 36);
        Gath Gn;
        if (prod) {
            if (((s + 1) & 3) == 0) {
                int k = (s + 1) >> 2;
                mi = midx[(b * 9 + k) * HWp + p0 + p];
                mv = mw[(b * 9 + k) * HWp + p0 + p];
            }
            Gn = issue(s + 1);
        }

        bf16x8 bfr[2];
        #pragma unroll
        for (int j = 0; j < 2; j++)
            bfr[j] = *(const bf16x8*)&S_lds[cur][(wn * 32 + j * 16 + lm) * 40 + lq * 8];
        bf16x8 af[4];
        af[0] = *(const bf16x8*)&Gc.a0;
        af[1] = *(const bf16x8*)&Gc.a1;
        af[2] = *(const bf16x8*)&Gc.a2;
        af[3] = *(const bf16x8*)&Gc.a3;
        #pragma unroll
        for (int i = 0; i < 4; i++)
            #pragma unroll
            for (int j = 0; j < 2; j++)
                acc[i][j] = __builtin_amdgcn_mfma_f32_16x16x32_bf16(
                    af[i], bfr[j], acc[i][j], 0, 0, 0);

        if (prod) {
            commitS(cur ^ 1, Gn);
            Gc = Gn;
        }
        __syncthreads();
    }

    // epilogue: C layout col(p)=lane&15, row(o)=(lane>>4)*4+reg
    #pragma unroll
    for (int i = 0; i < 4; i++) {
        #pragma unroll
        for (int r = 0; r < 4; r++) {
            int o = wm * 64 + i * 16 + lq * 4 + r;
            float bv = bias[o];
            float* orow = out + (size_t)(b * COUT_ + o) * HWp + p0 + wn * 32 + lm;
            #pragma unroll
            for (int j = 0; j < 2; j++)
                orow[j * 16] = acc[i][j][r] + bv;
        }
    }
}

extern "C" void kernel_launch(void* const* d_in, const int* in_sizes, int n_in,
                              void* d_out, int out_size, void* d_ws, size_t ws_size,
                              hipStream_t stream) {
    const float* x     = (const float*)d_in[0];
    const float* w_off = (const float*)d_in[1];
    const float* b_off = (const float*)d_in[2];
    const float* w     = (const float*)d_in[3];
    const float* bias  = (const float*)d_in[4];
    float* out = (float*)d_out;

    char* ws = (char*)d_ws;
    ushort* xt   = (ushort*)ws;                          // 8 MiB
    ushort* w_t2 = (ushort*)(ws + 8388608);              // 294912 B
    int4*   midx = (int4*)(ws + 8683520);                // 4.5 MiB
    float4* mwp  = (float4*)(ws + 13402112);             // 4.5 MiB

    prep_offsets_kernel<<<1344, 256, 0, stream>>>(x, w, w_off, b_off,
                                                  xt, w_t2, midx, mwp);
    deform_gemm_mfma<<<512, 256, 0, stream>>>(xt, w_t2, bias, midx, mwp, out);
}